// Round 1
// baseline (1648.557 us; speedup 1.0000x reference)
//
#include <hip/hip_runtime.h>
#include <hip/hip_bf16.h>
#include <stdint.h>

// ---------------------------------------------------------------------------
// GIN forward: embed -> 3x (aggregate + MLP)
// Strategy: build CSR once per launch (hist/scan/fill), gather-based
// aggregation fused with (1+eps)*h, register-blocked f32 matmul kernels.
// ---------------------------------------------------------------------------

// Detect whether edge_index is int64 (high words all zero for values < 2^31)
// or int32. One thread, writes flag.
__global__ void detect_i64_kernel(const unsigned int* ei, int* flag) {
    if (blockIdx.x == 0 && threadIdx.x == 0) {
        int is64 = 1;
        for (int e = 0; e < 64; ++e) {
            if (ei[2 * e + 1] != 0u) { is64 = 0; break; }
        }
        *flag = is64;
    }
}

__device__ __forceinline__ int edge_at(const int* ei32, int is64, long long pos) {
    if (is64) return (int)(((const long long*)ei32)[pos]);
    return ei32[pos];
}

__global__ void hist_kernel(const int* __restrict__ ei, const int* __restrict__ flag,
                            int* __restrict__ deg, int E) {
    int e = blockIdx.x * blockDim.x + threadIdx.x;
    if (e >= E) return;
    int is64 = *flag;
    int d = edge_at(ei, is64, (long long)E + e);
    atomicAdd(&deg[d], 1);
}

// Single-block exclusive scan over deg[0..n) -> offsets[0..n], cursor copy.
__global__ void scan_kernel(const int* __restrict__ deg, int* __restrict__ offsets,
                            int* __restrict__ cursor, int n) {
    __shared__ int sums[1024];
    const int tid = threadIdx.x;
    const int chunk = (n + 1023) >> 10;
    const int lo = tid * chunk;
    const int hi = min(lo + chunk, n);
    int s = 0;
    for (int i = lo; i < hi; ++i) s += deg[i];
    sums[tid] = s;
    __syncthreads();
    // Hillis-Steele inclusive scan
    for (int off = 1; off < 1024; off <<= 1) {
        int v = 0;
        if (tid >= off) v = sums[tid - off];
        __syncthreads();
        sums[tid] += v;
        __syncthreads();
    }
    int o = sums[tid] - s;  // exclusive prefix
    for (int i = lo; i < hi; ++i) {
        offsets[i] = o;
        cursor[i] = o;
        o += deg[i];
    }
    if (tid == 1023) offsets[n] = sums[1023];
}

__global__ void fill_kernel(const int* __restrict__ ei, const int* __restrict__ flag,
                            int* __restrict__ cursor, int* __restrict__ csr, int E) {
    int e = blockIdx.x * blockDim.x + threadIdx.x;
    if (e >= E) return;
    int is64 = *flag;
    int d = edge_at(ei, is64, (long long)E + e);
    int s = edge_at(ei, is64, (long long)e);
    int p = atomicAdd(&cursor[d], 1);
    csr[p] = s;
}

// Z[n] = (1+eps)*H[n] + sum_{j in N(n)} H[j]   (dim fixed at 128)
// 256 threads = 2 nodes/block, thread c = col.
__global__ __launch_bounds__(256) void aggz_kernel(
        const float* __restrict__ H, const int* __restrict__ offsets,
        const int* __restrict__ csr, const float* __restrict__ eps,
        float* __restrict__ Z, int n) {
    const int node = blockIdx.x * 2 + (threadIdx.x >> 7);
    const int c = threadIdx.x & 127;
    if (node >= n) return;
    const int beg = offsets[node];
    const int end = offsets[node + 1];
    float s = 0.f;
    int i = beg;
    // unroll by 2 to get two gathers in flight
    for (; i + 1 < end; i += 2) {
        int j0 = csr[i];
        int j1 = csr[i + 1];
        float v0 = H[(long long)j0 * 128 + c];
        float v1 = H[(long long)j1 * 128 + c];
        s += v0;
        s += v1;
    }
    if (i < end) {
        int j0 = csr[i];
        s += H[(long long)j0 * 128 + c];
    }
    const float h = H[(long long)node * 128 + c];
    Z[(long long)node * 128 + c] = (1.0f + eps[0]) * h + s;
}

// out[N x KOUT] = act(Zin[N x KIN] @ W[KIN x KOUT] + bias)
// Block: 256 threads, 32 rows. Thread tile: 8 rows x CT cols (CT=KOUT/64).
template<int KIN, int KOUT, bool RELU, bool HASBIAS>
__global__ __launch_bounds__(256) void mm_kernel(
        const float* __restrict__ Zin, const float* __restrict__ W,
        const float* __restrict__ bias, float* __restrict__ out) {
    constexpr int R = 32;
    constexpr int CT = KOUT / 64;
    __shared__ float xs[R * KIN];
    const int tid = threadIdx.x;
    const long long row0 = (long long)blockIdx.x * R;

    // cooperative vectorized load of the 32xKIN Z tile
    constexpr int TOT4 = R * KIN / 4;
    const float4* zsrc = (const float4*)(Zin + row0 * KIN);
    float4* xs4 = (float4*)xs;
#pragma unroll
    for (int i = 0; i < TOT4 / 256; ++i) xs4[tid + i * 256] = zsrc[tid + i * 256];
    __syncthreads();

    const int cg = tid & 63;   // 64 column groups
    const int rg = tid >> 6;   // 4 row groups of 8 rows
    const int c0 = cg * CT;
    const int r0 = rg * 8;

    float acc[8][CT];
#pragma unroll
    for (int r = 0; r < 8; ++r)
#pragma unroll
        for (int j = 0; j < CT; ++j) acc[r][j] = 0.f;

    for (int k4 = 0; k4 < KIN; k4 += 4) {
        float4 zr[8];
#pragma unroll
        for (int r = 0; r < 8; ++r)
            zr[r] = *(const float4*)&xs[(r0 + r) * KIN + k4];
#pragma unroll
        for (int kk = 0; kk < 4; ++kk) {
            float wv[CT];
            const float* wrow = W + (k4 + kk) * KOUT + c0;
            if constexpr (CT == 4) {
                float4 w4 = *(const float4*)wrow;
                wv[0] = w4.x; wv[1] = w4.y; wv[2] = w4.z; wv[3] = w4.w;
            } else {
                float2 w2 = *(const float2*)wrow;
                wv[0] = w2.x; wv[1] = w2.y;
            }
#pragma unroll
            for (int r = 0; r < 8; ++r) {
                float zv = (kk == 0) ? zr[r].x : (kk == 1) ? zr[r].y
                         : (kk == 2) ? zr[r].z : zr[r].w;
#pragma unroll
                for (int j = 0; j < CT; ++j)
                    acc[r][j] = fmaf(zv, wv[j], acc[r][j]);
            }
        }
    }

    float bv[CT];
#pragma unroll
    for (int j = 0; j < CT; ++j) bv[j] = HASBIAS ? bias[c0 + j] : 0.f;

#pragma unroll
    for (int r = 0; r < 8; ++r) {
        float v[CT];
#pragma unroll
        for (int j = 0; j < CT; ++j) {
            v[j] = acc[r][j] + bv[j];
            if (RELU) v[j] = fmaxf(v[j], 0.f);
        }
        float* op = out + (row0 + r0 + r) * KOUT + c0;
        if constexpr (CT == 4) {
            *(float4*)op = make_float4(v[0], v[1], v[2], v[3]);
        } else {
            *(float2*)op = make_float2(v[0], v[1]);
        }
    }
}

extern "C" void kernel_launch(void* const* d_in, const int* in_sizes, int n_in,
                              void* d_out, int out_size, void* d_ws, size_t ws_size,
                              hipStream_t stream) {
    const float* x    = (const float*)d_in[0];
    const int*   ei   = (const int*)d_in[1];
    const float* Wemb = (const float*)d_in[2];
    const float* eps1 = (const float*)d_in[3];
    const float* w1a  = (const float*)d_in[4];
    const float* b1a  = (const float*)d_in[5];
    const float* w1b  = (const float*)d_in[6];
    const float* b1b  = (const float*)d_in[7];
    const float* eps2 = (const float*)d_in[8];
    const float* w2a  = (const float*)d_in[9];
    const float* b2a  = (const float*)d_in[10];
    const float* w2b  = (const float*)d_in[11];
    const float* b2b  = (const float*)d_in[12];
    const float* eps3 = (const float*)d_in[13];
    const float* w3a  = (const float*)d_in[14];
    const float* b3a  = (const float*)d_in[15];
    const float* w3b  = (const float*)d_in[16];
    const float* b3b  = (const float*)d_in[17];

    const int N = in_sizes[0] / 64;   // 100000
    const int E = in_sizes[1] / 2;    // 1600000

    // workspace layout (256B aligned slices)
    char* ws = (char*)d_ws;
    size_t off = 0;
    auto alloc = [&](size_t bytes) -> void* {
        void* p = ws + off;
        off = (off + bytes + 255) & ~(size_t)255;
        return p;
    };
    float* H    = (float*)alloc((size_t)N * 128 * 4);
    float* Zb   = (float*)alloc((size_t)N * 128 * 4);
    float* T    = (float*)alloc((size_t)N * 256 * 4);
    int*   deg  = (int*)alloc((size_t)N * 4);
    int*   offs = (int*)alloc((size_t)(N + 1) * 4);
    int*   cur  = (int*)alloc((size_t)N * 4);
    int*   csr  = (int*)alloc((size_t)E * 4);
    int*   flag = (int*)alloc(256);

    // ---- CSR build (once; reused by all 3 layers) ----
    hipMemsetAsync(deg, 0, (size_t)N * 4, stream);
    detect_i64_kernel<<<1, 64, 0, stream>>>((const unsigned int*)ei, flag);
    hist_kernel<<<(E + 255) / 256, 256, 0, stream>>>(ei, flag, deg, E);
    scan_kernel<<<1, 1024, 0, stream>>>(deg, offs, cur, N);
    fill_kernel<<<(E + 255) / 256, 256, 0, stream>>>(ei, flag, cur, csr, E);

    const int MMB = N / 32;  // 3125 blocks (exact)

    // ---- embed: H = x @ W_embed ----
    mm_kernel<64, 128, false, false><<<MMB, 256, 0, stream>>>(x, Wemb, nullptr, H);

    // ---- layer 1: h = relu(z@w1a+b1a)@w1b + b1b ----
    aggz_kernel<<<N / 2, 256, 0, stream>>>(H, offs, csr, eps1, Zb, N);
    mm_kernel<128, 128, true,  true><<<MMB, 256, 0, stream>>>(Zb, w1a, b1a, T);
    mm_kernel<128, 128, false, true><<<MMB, 256, 0, stream>>>(T,  w1b, b1b, H);

    // ---- layer 2: h = relu(relu(z@w2a+b2a)@w2b + b2b) ----
    aggz_kernel<<<N / 2, 256, 0, stream>>>(H, offs, csr, eps2, Zb, N);
    mm_kernel<128, 256, true, true><<<MMB, 256, 0, stream>>>(Zb, w2a, b2a, T);
    mm_kernel<256, 128, true, true><<<MMB, 256, 0, stream>>>(T,  w2b, b2b, H);

    // ---- layer 3 ----
    aggz_kernel<<<N / 2, 256, 0, stream>>>(H, offs, csr, eps3, Zb, N);
    mm_kernel<128, 256, true, true><<<MMB, 256, 0, stream>>>(Zb, w3a, b3a, T);
    mm_kernel<256, 128, true, true><<<MMB, 256, 0, stream>>>(T,  w3b, b3b, (float*)d_out);
}

// Round 2
// 844.388 us; speedup vs baseline: 1.9524x; 1.9524x over previous
//
#include <hip/hip_runtime.h>
#include <hip/hip_bf16.h>
#include <stdint.h>

// ---------------------------------------------------------------------------
// GIN forward, round 2: bf16 MFMA matmuls (LDS-free, packed-B fragments),
// bf16 activation pipeline, multi-block scan for CSR build.
// ---------------------------------------------------------------------------

typedef __attribute__((ext_vector_type(8))) short short8;
typedef __attribute__((ext_vector_type(4))) float float4v;

__device__ __forceinline__ float b2f_lo(unsigned int u) {
    return __uint_as_float(u << 16);
}
__device__ __forceinline__ float b2f_hi(unsigned int u) {
    return __uint_as_float(u & 0xffff0000u);
}
__device__ __forceinline__ unsigned short f2b(float f) {
    unsigned int u = __float_as_uint(f);
    return (unsigned short)((u + 0x7fffu + ((u >> 16) & 1u)) >> 16);  // RNE
}

// ---------------- edge-index dtype detection ----------------
__global__ void detect_i64_kernel(const unsigned int* ei, int* flag) {
    if (threadIdx.x == 0) {
        int is64 = 1;
        for (int e = 0; e < 64; ++e)
            if (ei[2 * e + 1] != 0u) { is64 = 0; break; }
        *flag = is64;
    }
}

__device__ __forceinline__ int edge_at(const int* ei32, int is64, long long pos) {
    if (is64) return (int)(((const long long*)ei32)[pos]);
    return ei32[pos];
}

// ---------------- CSR build ----------------
__global__ void hist_kernel(const int* __restrict__ ei, const int* __restrict__ flag,
                            int* __restrict__ deg, int E) {
    int e = blockIdx.x * blockDim.x + threadIdx.x;
    if (e >= E) return;
    int d = edge_at(ei, *flag, (long long)E + e);
    atomicAdd(&deg[d], 1);
}

// per-1024-block local exclusive scan; offs[i] = local exclusive, partial[b] = block sum
__global__ __launch_bounds__(1024) void scan1_kernel(
        const int* __restrict__ deg, int* __restrict__ offs,
        int* __restrict__ partial, int n) {
    __shared__ int sm[1024];
    const int t = threadIdx.x;
    const int i = blockIdx.x * 1024 + t;
    int v = (i < n) ? deg[i] : 0;
    sm[t] = v;
    __syncthreads();
#pragma unroll
    for (int off = 1; off < 1024; off <<= 1) {
        int x = (t >= off) ? sm[t - off] : 0;
        __syncthreads();
        sm[t] += x;
        __syncthreads();
    }
    if (i < n) offs[i] = sm[t] - v;
    if (t == 1023) partial[blockIdx.x] = sm[1023];
}

// single small block scans the per-block partials (G1 <= 128)
__global__ __launch_bounds__(128) void scan2_kernel(
        int* __restrict__ partial, int* __restrict__ blockoff, int g1) {
    __shared__ int sm[128];
    const int t = threadIdx.x;
    int v = (t < g1) ? partial[t] : 0;
    sm[t] = v;
    __syncthreads();
#pragma unroll
    for (int off = 1; off < 128; off <<= 1) {
        int x = (t >= off) ? sm[t - off] : 0;
        __syncthreads();
        sm[t] += x;
        __syncthreads();
    }
    blockoff[t] = sm[t] - v;
}

__global__ __launch_bounds__(1024) void scan3_kernel(
        int* __restrict__ offs, int* __restrict__ cursor,
        const int* __restrict__ blockoff, int n, int E) {
    const int i = blockIdx.x * 1024 + threadIdx.x;
    if (i < n) {
        int v = offs[i] + blockoff[blockIdx.x];
        offs[i] = v;
        cursor[i] = v;
    }
    if (i == 0) offs[n] = E;
}

__global__ void fill_kernel(const int* __restrict__ ei, const int* __restrict__ flag,
                            int* __restrict__ cursor, int* __restrict__ csr, int E) {
    int e = blockIdx.x * blockDim.x + threadIdx.x;
    if (e >= E) return;
    int is64 = *flag;
    int d = edge_at(ei, is64, (long long)E + e);
    int s = edge_at(ei, is64, (long long)e);
    int p = atomicAdd(&cursor[d], 1);
    csr[p] = s;
}

// ---------------- conversions ----------------
// x (f32, N*64) -> bf16 padded buffer (Mpad*64), pad rows zeroed
__global__ void xconv_kernel(const float* __restrict__ x, unsigned short* __restrict__ xb,
                             int total_real, int total_pad) {
    int i = blockIdx.x * blockDim.x + threadIdx.x;
    if (i >= total_pad) return;
    xb[i] = (i < total_real) ? f2b(x[i]) : (unsigned short)0;
}

// Pack W[K x KOUT] (f32 row-major) into MFMA-B fragment order:
// out[(((t*KS + s)*64 + l)*8 + j] = bf16(W[(s*32 + (l>>4)*8 + j)*KOUT + t*16 + (l&15)])
__global__ void packw_kernel(const float* __restrict__ W, unsigned short* __restrict__ out,
                             int K, int KOUT) {
    const int KS = K / 32;
    const int total = (KOUT / 16) * KS * 64;
    int id = blockIdx.x * blockDim.x + threadIdx.x;
    if (id >= total) return;
    const int l = id & 63;
    const int s = (id >> 6) % KS;
    const int t = id / (KS * 64);
    const int kbase = s * 32 + ((l >> 4) << 3);
    const int n = t * 16 + (l & 15);
#pragma unroll
    for (int j = 0; j < 8; ++j)
        out[(long long)id * 8 + j] = f2b(W[(long long)(kbase + j) * KOUT + n]);
}

// ---------------- aggregation: Z = (1+eps)*H + sum_{j in N(i)} H[j], bf16 ----------------
// 256 threads = 4 nodes/block, 64 threads/node, 2 cols/thread (4B packed loads).
__global__ __launch_bounds__(256) void aggz_kernel(
        const unsigned short* __restrict__ H, const int* __restrict__ offs,
        const int* __restrict__ csr, const float* __restrict__ eps,
        unsigned short* __restrict__ Z, int n) {
    const int node = blockIdx.x * 4 + (threadIdx.x >> 6);
    const int c2 = (threadIdx.x & 63) << 1;  // column pair base
    if (node >= n) return;
    const int beg = offs[node];
    const int end = offs[node + 1];
    float s0 = 0.f, s1 = 0.f;
    int i = beg;
    for (; i + 1 < end; i += 2) {
        int j0 = csr[i];
        int j1 = csr[i + 1];
        unsigned int u0 = *(const unsigned int*)(H + ((long long)j0 << 7) + c2);
        unsigned int u1 = *(const unsigned int*)(H + ((long long)j1 << 7) + c2);
        s0 += b2f_lo(u0) + b2f_lo(u1);
        s1 += b2f_hi(u0) + b2f_hi(u1);
    }
    if (i < end) {
        int j0 = csr[i];
        unsigned int u0 = *(const unsigned int*)(H + ((long long)j0 << 7) + c2);
        s0 += b2f_lo(u0);
        s1 += b2f_hi(u0);
    }
    unsigned int uh = *(const unsigned int*)(H + ((long long)node << 7) + c2);
    const float e = 1.0f + eps[0];
    float z0 = fmaf(e, b2f_lo(uh), s0);
    float z1 = fmaf(e, b2f_hi(uh), s1);
    *(unsigned int*)(Z + ((long long)node << 7) + c2) =
        ((unsigned int)f2b(z1) << 16) | (unsigned int)f2b(z0);
}

// ---------------- MFMA matmul ----------------
// out[M x KOUT] = act(Zin[M x KIN] @ W[KIN x KOUT] + bias)
// Block = 256 threads = 4 waves; wave w computes rows [blk*64 + w*16, +16) x KOUT.
// A frags read straight from row-major bf16 Zin (16B/lane); B frags from packed Wp.
// No LDS, no barriers.
template<int KIN, int KOUT, bool RELU, bool HASBIAS, bool OUTF32>
__global__ __launch_bounds__(256) void mm_mfma(
        const unsigned short* __restrict__ Zin, const unsigned short* __restrict__ Wp,
        const float* __restrict__ bias, void* __restrict__ outv, int Mreal) {
    constexpr int KS = KIN / 32;
    constexpr int NT = KOUT / 16;
    const int tid = threadIdx.x;
    const int w = tid >> 6;
    const int l = tid & 63;
    const int lm = l & 15;       // A row within tile / B+D col within tile
    const int lk = l >> 4;       // k-group (A/B) / row-group (D)
    const long long arow = (long long)blockIdx.x * 64 + w * 16 + lm;
    const unsigned short* zrow = Zin + arow * KIN + lk * 8;

    float4v acc[NT];
#pragma unroll
    for (int t = 0; t < NT; ++t) acc[t] = (float4v){0.f, 0.f, 0.f, 0.f};

#pragma unroll
    for (int s = 0; s < KS; ++s) {
        short8 a = *(const short8*)(zrow + s * 32);
#pragma unroll
        for (int t = 0; t < NT; ++t) {
            short8 b = *(const short8*)(Wp + (long long)((t * KS + s) * 64 + l) * 8);
            acc[t] = __builtin_amdgcn_mfma_f32_16x16x32_bf16(a, b, acc[t], 0, 0, 0);
        }
    }

    // D layout: col = lane&15 (within tile), row = (lane>>4)*4 + r
    const long long orow0 = (long long)blockIdx.x * 64 + w * 16 + lk * 4;
#pragma unroll
    for (int t = 0; t < NT; ++t) {
        const int n = t * 16 + lm;
        const float bv = HASBIAS ? bias[n] : 0.f;
#pragma unroll
        for (int r = 0; r < 4; ++r) {
            float v = acc[t][r] + bv;
            if (RELU) v = fmaxf(v, 0.f);
            const long long orow = orow0 + r;
            if (OUTF32) {
                if (orow < Mreal) ((float*)outv)[orow * KOUT + n] = v;
            } else {
                ((unsigned short*)outv)[orow * KOUT + n] = f2b(v);
            }
        }
    }
}

extern "C" void kernel_launch(void* const* d_in, const int* in_sizes, int n_in,
                              void* d_out, int out_size, void* d_ws, size_t ws_size,
                              hipStream_t stream) {
    const float* x    = (const float*)d_in[0];
    const int*   ei   = (const int*)d_in[1];
    const float* Wemb = (const float*)d_in[2];
    const float* eps1 = (const float*)d_in[3];
    const float* w1a  = (const float*)d_in[4];
    const float* b1a  = (const float*)d_in[5];
    const float* w1b  = (const float*)d_in[6];
    const float* b1b  = (const float*)d_in[7];
    const float* eps2 = (const float*)d_in[8];
    const float* w2a  = (const float*)d_in[9];
    const float* b2a  = (const float*)d_in[10];
    const float* w2b  = (const float*)d_in[11];
    const float* b2b  = (const float*)d_in[12];
    const float* eps3 = (const float*)d_in[13];
    const float* w3a  = (const float*)d_in[14];
    const float* b3a  = (const float*)d_in[15];
    const float* w3b  = (const float*)d_in[16];
    const float* b3b  = (const float*)d_in[17];

    const int N = in_sizes[0] / 64;   // 100000
    const int E = in_sizes[1] / 2;    // 1600000
    const int Mpad = ((N + 63) / 64) * 64;  // 100032

    char* ws = (char*)d_ws;
    size_t off = 0;
    auto alloc = [&](size_t bytes) -> void* {
        void* p = ws + off;
        off = (off + bytes + 255) & ~(size_t)255;
        return p;
    };
    unsigned short* xb  = (unsigned short*)alloc((size_t)Mpad * 64 * 2);
    unsigned short* Hb  = (unsigned short*)alloc((size_t)Mpad * 128 * 2);
    unsigned short* Zb  = (unsigned short*)alloc((size_t)Mpad * 128 * 2);
    unsigned short* Tb  = (unsigned short*)alloc((size_t)Mpad * 256 * 2);
    unsigned short* pWe = (unsigned short*)alloc((size_t)64 * 128 * 2);
    unsigned short* p1a = (unsigned short*)alloc((size_t)128 * 128 * 2);
    unsigned short* p1b = (unsigned short*)alloc((size_t)128 * 128 * 2);
    unsigned short* p2a = (unsigned short*)alloc((size_t)128 * 256 * 2);
    unsigned short* p2b = (unsigned short*)alloc((size_t)256 * 128 * 2);
    unsigned short* p3a = (unsigned short*)alloc((size_t)128 * 256 * 2);
    unsigned short* p3b = (unsigned short*)alloc((size_t)256 * 128 * 2);
    int* deg   = (int*)alloc((size_t)N * 4);
    int* offs  = (int*)alloc((size_t)(N + 1) * 4);
    int* cur   = (int*)alloc((size_t)N * 4);
    int* csr   = (int*)alloc((size_t)E * 4);
    int* part  = (int*)alloc(1024);
    int* boff  = (int*)alloc(1024);
    int* flag  = (int*)alloc(256);

    const int G1 = (N + 1023) / 1024;  // 98

    // ---- CSR build ----
    hipMemsetAsync(deg, 0, (size_t)N * 4, stream);
    detect_i64_kernel<<<1, 64, 0, stream>>>((const unsigned int*)ei, flag);
    hist_kernel<<<(E + 255) / 256, 256, 0, stream>>>(ei, flag, deg, E);
    scan1_kernel<<<G1, 1024, 0, stream>>>(deg, offs, part, N);
    scan2_kernel<<<1, 128, 0, stream>>>(part, boff, G1);
    scan3_kernel<<<G1, 1024, 0, stream>>>(offs, cur, boff, N, E);
    fill_kernel<<<(E + 255) / 256, 256, 0, stream>>>(ei, flag, cur, csr, E);

    // ---- conversions / weight packing ----
    xconv_kernel<<<(Mpad * 64 + 255) / 256, 256, 0, stream>>>(x, xb, N * 64, Mpad * 64);
    auto packw = [&](const float* W, unsigned short* o, int K, int KOUT) {
        int tot = (KOUT / 16) * (K / 32) * 64;
        packw_kernel<<<(tot + 255) / 256, 256, 0, stream>>>(W, o, K, KOUT);
    };
    packw(Wemb, pWe, 64, 128);
    packw(w1a, p1a, 128, 128);
    packw(w1b, p1b, 128, 128);
    packw(w2a, p2a, 128, 256);
    packw(w2b, p2b, 256, 128);
    packw(w3a, p3a, 128, 256);
    packw(w3b, p3b, 256, 128);

    const int MMB = Mpad / 64;  // 1563

    // ---- embed: H = x @ W_embed ----
    mm_mfma<64, 128, false, false, false><<<MMB, 256, 0, stream>>>(xb, pWe, nullptr, Hb, N);

    // ---- layer 1 ----
    aggz_kernel<<<N / 4, 256, 0, stream>>>(Hb, offs, csr, eps1, Zb, N);
    mm_mfma<128, 128, true,  true, false><<<MMB, 256, 0, stream>>>(Zb, p1a, b1a, Tb, N);
    mm_mfma<128, 128, false, true, false><<<MMB, 256, 0, stream>>>(Tb, p1b, b1b, Hb, N);

    // ---- layer 2 ----
    aggz_kernel<<<N / 4, 256, 0, stream>>>(Hb, offs, csr, eps2, Zb, N);
    mm_mfma<128, 256, true, true, false><<<MMB, 256, 0, stream>>>(Zb, p2a, b2a, Tb, N);
    mm_mfma<256, 128, true, true, false><<<MMB, 256, 0, stream>>>(Tb, p2b, b2b, Hb, N);

    // ---- layer 3 (final store f32 to d_out, row-guarded) ----
    aggz_kernel<<<N / 4, 256, 0, stream>>>(Hb, offs, csr, eps3, Zb, N);
    mm_mfma<128, 256, true, true, false><<<MMB, 256, 0, stream>>>(Zb, p3a, b3a, Tb, N);
    mm_mfma<256, 128, true, true, true><<<MMB, 256, 0, stream>>>(Tb, p3b, b3b, d_out, N);
}

// Round 3
// 699.479 us; speedup vs baseline: 2.3568x; 1.2072x over previous
//
#include <hip/hip_runtime.h>
#include <hip/hip_bf16.h>
#include <stdint.h>

// ---------------------------------------------------------------------------
// GIN forward, round 3: radix-partition CSR build (no global atomics, no
// scattered full-line writes), bf16 MFMA matmuls, bf16 activations.
// ---------------------------------------------------------------------------

typedef __attribute__((ext_vector_type(8))) short short8;
typedef __attribute__((ext_vector_type(4))) float float4v;

#define BKT 512       // nodes per bucket (dst >> 9)
#define NBMAX 256     // max buckets held in LDS (NB = 196 here)

__device__ __forceinline__ float b2f_lo(unsigned int u) {
    return __uint_as_float(u << 16);
}
__device__ __forceinline__ float b2f_hi(unsigned int u) {
    return __uint_as_float(u & 0xffff0000u);
}
__device__ __forceinline__ unsigned short f2b(float f) {
    unsigned int u = __float_as_uint(f);
    return (unsigned short)((u + 0x7fffu + ((u >> 16) & 1u)) >> 16);  // RNE
}

// ---------------- edge-index dtype detection ----------------
__global__ void detect_i64_kernel(const unsigned int* ei, int* flag) {
    if (threadIdx.x == 0) {
        int is64 = 1;
        for (int e = 0; e < 64; ++e)
            if (ei[2 * e + 1] != 0u) { is64 = 0; break; }
        *flag = is64;
    }
}

__device__ __forceinline__ int edge_at(const int* ei32, int is64, long long pos) {
    if (is64) return (int)(((const long long*)ei32)[pos]);
    return ei32[pos];
}

// unpack edge_index into src/dst i32 arrays (coalesced)
__global__ void econv_kernel(const int* __restrict__ ei, const int* __restrict__ flag,
                             int* __restrict__ srcs, int* __restrict__ dsts, int E) {
    int e = blockIdx.x * blockDim.x + threadIdx.x;
    if (e >= E) return;
    int is64 = *flag;
    srcs[e] = edge_at(ei, is64, e);
    dsts[e] = edge_at(ei, is64, (long long)E + e);
}

// ---------------- radix partition pass 1: per-(block,bucket) histogram ----------------
__global__ __launch_bounds__(256) void part_hist_kernel(
        const int* __restrict__ dsts, int* __restrict__ bh, int E, int NB, int PB) {
    __shared__ int h[NBMAX];
    const int g = blockIdx.x, tid = threadIdx.x;
    for (int i = tid; i < NB; i += 256) h[i] = 0;
    __syncthreads();
    const int e0 = g * PB, e1 = min(e0 + PB, E);
    for (int e = e0 + tid; e < e1; e += 256)
        atomicAdd(&h[dsts[e] >> 9], 1);
    __syncthreads();
    for (int i = tid; i < NB; i += 256) bh[i * gridDim.x + g] = h[i];
}

// ---------------- generic multi-block exclusive scan ----------------
__global__ __launch_bounds__(1024) void scan1_kernel(
        const int* __restrict__ in, int* __restrict__ out,
        int* __restrict__ partial, int n) {
    __shared__ int sm[1024];
    const int t = threadIdx.x;
    const int i = blockIdx.x * 1024 + t;
    int v = (i < n) ? in[i] : 0;
    sm[t] = v;
    __syncthreads();
#pragma unroll
    for (int off = 1; off < 1024; off <<= 1) {
        int x = (t >= off) ? sm[t - off] : 0;
        __syncthreads();
        sm[t] += x;
        __syncthreads();
    }
    if (i < n) out[i] = sm[t] - v;
    if (t == 1023) partial[blockIdx.x] = sm[1023];
}

__global__ __launch_bounds__(128) void scan2_kernel(
        int* __restrict__ partial, int* __restrict__ blockoff, int g1) {
    __shared__ int sm[128];
    const int t = threadIdx.x;
    int v = (t < g1) ? partial[t] : 0;
    sm[t] = v;
    __syncthreads();
#pragma unroll
    for (int off = 1; off < 128; off <<= 1) {
        int x = (t >= off) ? sm[t - off] : 0;
        __syncthreads();
        sm[t] += x;
        __syncthreads();
    }
    blockoff[t] = sm[t] - v;
}

__global__ __launch_bounds__(1024) void scan3g_kernel(
        int* __restrict__ a, const int* __restrict__ blockoff, int n) {
    int i = blockIdx.x * 1024 + threadIdx.x;
    if (i < n) a[i] += blockoff[blockIdx.x];
}

// ---------------- pass 2: scatter edges into bucket-contiguous staging ----------------
// staged entry: (dlocal<<17) | src   (dlocal<512 -> 9 bits; src<2^17)
__global__ __launch_bounds__(256) void part_scatter_kernel(
        const int* __restrict__ dsts, const int* __restrict__ srcs,
        const int* __restrict__ bhs, unsigned int* __restrict__ staged,
        int E, int NB, int PB) {
    __shared__ int cur[NBMAX];
    const int g = blockIdx.x, tid = threadIdx.x;
    for (int i = tid; i < NB; i += 256) cur[i] = bhs[i * gridDim.x + g];
    __syncthreads();
    const int e0 = g * PB, e1 = min(e0 + PB, E);
    for (int e = e0 + tid; e < e1; e += 256) {
        int d = dsts[e];
        int s = srcs[e];
        int b = d >> 9;
        int p = atomicAdd(&cur[b], 1);
        staged[p] = ((unsigned int)(d & (BKT - 1)) << 17) | (unsigned int)s;
    }
}

// ---------------- pass 3: per-bucket counting sort -> offs + csr ----------------
__global__ __launch_bounds__(256) void csr_local_kernel(
        const unsigned int* __restrict__ staged, const int* __restrict__ bhs,
        int* __restrict__ offs, int* __restrict__ csr, int N, int E, int NB, int G2) {
    __shared__ int hist[BKT];
    __shared__ int cur[BKT];
    const int b = blockIdx.x;
    const int tid = threadIdx.x;
    const int start = bhs[b * G2];
    const int end = (b + 1 < NB) ? bhs[(b + 1) * G2] : E;
    const int node0 = b * BKT;
    for (int i = tid; i < BKT; i += 256) hist[i] = 0;
    __syncthreads();
    for (int i = start + tid; i < end; i += 256)
        atomicAdd(&hist[staged[i] >> 17], 1);
    __syncthreads();
    // inclusive Hillis-Steele scan of hist[0..511], 2 elements/thread
    const int i0 = tid * 2, i1 = i0 + 1;
    for (int off = 1; off < BKT; off <<= 1) {
        int v0 = (i0 >= off) ? hist[i0 - off] : 0;
        int v1 = (i1 >= off) ? hist[i1 - off] : 0;
        __syncthreads();
        hist[i0] += v0;
        hist[i1] += v1;
        __syncthreads();
    }
    for (int i = tid; i < BKT; i += 256) {
        int node = node0 + i;
        if (node < N) {
            int e0 = start + ((i == 0) ? 0 : hist[i - 1]);
            offs[node] = e0;
            cur[i] = e0;
        }
    }
    if (b == NB - 1 && tid == 0) offs[N] = E;
    __syncthreads();
    for (int i = start + tid; i < end; i += 256) {
        unsigned int v = staged[i];
        int dl = v >> 17;
        int src = (int)(v & 0x1ffff);
        int p = atomicAdd(&cur[dl], 1);
        csr[p] = src;
    }
}

// ---------------- conversions ----------------
__global__ void xconv_kernel(const float* __restrict__ x, unsigned short* __restrict__ xb,
                             int total_real, int total_pad) {
    int i = blockIdx.x * blockDim.x + threadIdx.x;
    if (i >= total_pad) return;
    xb[i] = (i < total_real) ? f2b(x[i]) : (unsigned short)0;
}

// Pack W[K x KOUT] (f32 row-major) into MFMA-B fragment order.
__global__ void packw_kernel(const float* __restrict__ W, unsigned short* __restrict__ out,
                             int K, int KOUT) {
    const int KS = K / 32;
    const int total = (KOUT / 16) * KS * 64;
    int id = blockIdx.x * blockDim.x + threadIdx.x;
    if (id >= total) return;
    const int l = id & 63;
    const int s = (id >> 6) % KS;
    const int t = id / (KS * 64);
    const int kbase = s * 32 + ((l >> 4) << 3);
    const int n = t * 16 + (l & 15);
#pragma unroll
    for (int j = 0; j < 8; ++j)
        out[(long long)id * 8 + j] = f2b(W[(long long)(kbase + j) * KOUT + n]);
}

// ---------------- aggregation: Z = (1+eps)*H + sum_{j in N(i)} H[j], bf16 ----------------
__global__ __launch_bounds__(256) void aggz_kernel(
        const unsigned short* __restrict__ H, const int* __restrict__ offs,
        const int* __restrict__ csr, const float* __restrict__ eps,
        unsigned short* __restrict__ Z, int n) {
    const int node = blockIdx.x * 4 + (threadIdx.x >> 6);
    const int c2 = (threadIdx.x & 63) << 1;
    if (node >= n) return;
    const int beg = offs[node];
    const int end = offs[node + 1];
    float s0 = 0.f, s1 = 0.f;
    int i = beg;
    for (; i + 1 < end; i += 2) {
        int j0 = csr[i];
        int j1 = csr[i + 1];
        unsigned int u0 = *(const unsigned int*)(H + ((long long)j0 << 7) + c2);
        unsigned int u1 = *(const unsigned int*)(H + ((long long)j1 << 7) + c2);
        s0 += b2f_lo(u0) + b2f_lo(u1);
        s1 += b2f_hi(u0) + b2f_hi(u1);
    }
    if (i < end) {
        int j0 = csr[i];
        unsigned int u0 = *(const unsigned int*)(H + ((long long)j0 << 7) + c2);
        s0 += b2f_lo(u0);
        s1 += b2f_hi(u0);
    }
    unsigned int uh = *(const unsigned int*)(H + ((long long)node << 7) + c2);
    const float e = 1.0f + eps[0];
    float z0 = fmaf(e, b2f_lo(uh), s0);
    float z1 = fmaf(e, b2f_hi(uh), s1);
    *(unsigned int*)(Z + ((long long)node << 7) + c2) =
        ((unsigned int)f2b(z1) << 16) | (unsigned int)f2b(z0);
}

// ---------------- MFMA matmul (LDS-free, packed-B fragments) ----------------
template<int KIN, int KOUT, bool RELU, bool HASBIAS, bool OUTF32>
__global__ __launch_bounds__(256) void mm_mfma(
        const unsigned short* __restrict__ Zin, const unsigned short* __restrict__ Wp,
        const float* __restrict__ bias, void* __restrict__ outv, int Mreal) {
    constexpr int KS = KIN / 32;
    constexpr int NT = KOUT / 16;
    const int tid = threadIdx.x;
    const int w = tid >> 6;
    const int l = tid & 63;
    const int lm = l & 15;
    const int lk = l >> 4;
    const long long arow = (long long)blockIdx.x * 64 + w * 16 + lm;
    const unsigned short* zrow = Zin + arow * KIN + lk * 8;

    float4v acc[NT];
#pragma unroll
    for (int t = 0; t < NT; ++t) acc[t] = (float4v){0.f, 0.f, 0.f, 0.f};

#pragma unroll
    for (int s = 0; s < KS; ++s) {
        short8 a = *(const short8*)(zrow + s * 32);
#pragma unroll
        for (int t = 0; t < NT; ++t) {
            short8 b = *(const short8*)(Wp + (long long)((t * KS + s) * 64 + l) * 8);
            acc[t] = __builtin_amdgcn_mfma_f32_16x16x32_bf16(a, b, acc[t], 0, 0, 0);
        }
    }

    const long long orow0 = (long long)blockIdx.x * 64 + w * 16 + lk * 4;
#pragma unroll
    for (int t = 0; t < NT; ++t) {
        const int n = t * 16 + lm;
        const float bv = HASBIAS ? bias[n] : 0.f;
#pragma unroll
        for (int r = 0; r < 4; ++r) {
            float v = acc[t][r] + bv;
            if (RELU) v = fmaxf(v, 0.f);
            const long long orow = orow0 + r;
            if (OUTF32) {
                if (orow < Mreal) ((float*)outv)[orow * KOUT + n] = v;
            } else {
                ((unsigned short*)outv)[orow * KOUT + n] = f2b(v);
            }
        }
    }
}

extern "C" void kernel_launch(void* const* d_in, const int* in_sizes, int n_in,
                              void* d_out, int out_size, void* d_ws, size_t ws_size,
                              hipStream_t stream) {
    const float* x    = (const float*)d_in[0];
    const int*   ei   = (const int*)d_in[1];
    const float* Wemb = (const float*)d_in[2];
    const float* eps1 = (const float*)d_in[3];
    const float* w1a  = (const float*)d_in[4];
    const float* b1a  = (const float*)d_in[5];
    const float* w1b  = (const float*)d_in[6];
    const float* b1b  = (const float*)d_in[7];
    const float* eps2 = (const float*)d_in[8];
    const float* w2a  = (const float*)d_in[9];
    const float* b2a  = (const float*)d_in[10];
    const float* w2b  = (const float*)d_in[11];
    const float* b2b  = (const float*)d_in[12];
    const float* eps3 = (const float*)d_in[13];
    const float* w3a  = (const float*)d_in[14];
    const float* b3a  = (const float*)d_in[15];
    const float* w3b  = (const float*)d_in[16];
    const float* b3b  = (const float*)d_in[17];

    const int N = in_sizes[0] / 64;   // 100000
    const int E = in_sizes[1] / 2;    // 1600000
    const int Mpad = ((N + 63) / 64) * 64;
    const int NB = (N + BKT - 1) / BKT;   // 196
    const int G2 = 256;                    // partition blocks
    const int PB = (E + G2 - 1) / G2;      // edges per partition block
    const int BH = NB * G2;                // 50176

    char* ws = (char*)d_ws;
    size_t off = 0;
    auto alloc = [&](size_t bytes) -> void* {
        void* p = ws + off;
        off = (off + bytes + 255) & ~(size_t)255;
        return p;
    };
    unsigned short* xb  = (unsigned short*)alloc((size_t)Mpad * 64 * 2);
    unsigned short* Hb  = (unsigned short*)alloc((size_t)Mpad * 128 * 2);
    unsigned short* Zb  = (unsigned short*)alloc((size_t)Mpad * 128 * 2);
    unsigned short* Tb  = (unsigned short*)alloc((size_t)Mpad * 256 * 2);
    unsigned short* pWe = (unsigned short*)alloc((size_t)64 * 128 * 2);
    unsigned short* p1a = (unsigned short*)alloc((size_t)128 * 128 * 2);
    unsigned short* p1b = (unsigned short*)alloc((size_t)128 * 128 * 2);
    unsigned short* p2a = (unsigned short*)alloc((size_t)128 * 256 * 2);
    unsigned short* p2b = (unsigned short*)alloc((size_t)256 * 128 * 2);
    unsigned short* p3a = (unsigned short*)alloc((size_t)128 * 256 * 2);
    unsigned short* p3b = (unsigned short*)alloc((size_t)256 * 128 * 2);
    int* offs = (int*)alloc((size_t)(N + 1) * 4);
    int* csr  = (int*)alloc((size_t)E * 4);
    int* bh   = (int*)alloc((size_t)BH * 4);
    int* bhs  = (int*)alloc((size_t)BH * 4);
    int* part = (int*)alloc(1024);
    int* boff = (int*)alloc(1024);
    int* flag = (int*)alloc(256);

    // CSR staging aliased into Tb (Tb first used only in the mm phase, which
    // runs after the CSR build in-stream). staged: E*4, dsts: E*4, srcs: E*4.
    unsigned int* staged = (unsigned int*)Tb;
    int* dsts = (int*)(Tb + (size_t)E * 2);        // byte offset E*4
    int* srcs = (int*)(Tb + (size_t)E * 4);        // byte offset E*8

    // ---- CSR build (radix partition + per-bucket counting sort) ----
    detect_i64_kernel<<<1, 64, 0, stream>>>((const unsigned int*)ei, flag);
    econv_kernel<<<(E + 255) / 256, 256, 0, stream>>>(ei, flag, srcs, dsts, E);
    part_hist_kernel<<<G2, 256, 0, stream>>>(dsts, bh, E, NB, PB);
    const int G1 = (BH + 1023) / 1024;  // 49
    scan1_kernel<<<G1, 1024, 0, stream>>>(bh, bhs, part, BH);
    scan2_kernel<<<1, 128, 0, stream>>>(part, boff, G1);
    scan3g_kernel<<<G1, 1024, 0, stream>>>(bhs, boff, BH);
    part_scatter_kernel<<<G2, 256, 0, stream>>>(dsts, srcs, bhs, staged, E, NB, PB);
    csr_local_kernel<<<NB, 256, 0, stream>>>(staged, bhs, offs, csr, N, E, NB, G2);

    // ---- conversions / weight packing ----
    xconv_kernel<<<(Mpad * 64 + 255) / 256, 256, 0, stream>>>(x, xb, N * 64, Mpad * 64);
    auto packw = [&](const float* W, unsigned short* o, int K, int KOUT) {
        int tot = (KOUT / 16) * (K / 32) * 64;
        packw_kernel<<<(tot + 255) / 256, 256, 0, stream>>>(W, o, K, KOUT);
    };
    packw(Wemb, pWe, 64, 128);
    packw(w1a, p1a, 128, 128);
    packw(w1b, p1b, 128, 128);
    packw(w2a, p2a, 128, 256);
    packw(w2b, p2b, 256, 128);
    packw(w3a, p3a, 128, 256);
    packw(w3b, p3b, 256, 128);

    const int MMB = Mpad / 64;

    // ---- embed ----
    mm_mfma<64, 128, false, false, false><<<MMB, 256, 0, stream>>>(xb, pWe, nullptr, Hb, N);

    // ---- layer 1 ----
    aggz_kernel<<<(N + 3) / 4, 256, 0, stream>>>(Hb, offs, csr, eps1, Zb, N);
    mm_mfma<128, 128, true,  true, false><<<MMB, 256, 0, stream>>>(Zb, p1a, b1a, Tb, N);
    mm_mfma<128, 128, false, true, false><<<MMB, 256, 0, stream>>>(Tb, p1b, b1b, Hb, N);

    // ---- layer 2 ----
    aggz_kernel<<<(N + 3) / 4, 256, 0, stream>>>(Hb, offs, csr, eps2, Zb, N);
    mm_mfma<128, 256, true, true, false><<<MMB, 256, 0, stream>>>(Zb, p2a, b2a, Tb, N);
    mm_mfma<256, 128, true, true, false><<<MMB, 256, 0, stream>>>(Tb, p2b, b2b, Hb, N);

    // ---- layer 3 ----
    aggz_kernel<<<(N + 3) / 4, 256, 0, stream>>>(Hb, offs, csr, eps3, Zb, N);
    mm_mfma<128, 256, true, true, false><<<MMB, 256, 0, stream>>>(Zb, p3a, b3a, Tb, N);
    mm_mfma<256, 128, true, true, true><<<MMB, 256, 0, stream>>>(Tb, p3b, b3b, d_out, N);
}

// Round 4
// 693.242 us; speedup vs baseline: 2.3780x; 1.0090x over previous
//
#include <hip/hip_runtime.h>
#include <hip/hip_bf16.h>
#include <stdint.h>

// ---------------------------------------------------------------------------
// GIN forward, round 4: XCD-sliced aggregation (H stored slice-major, 8
// slices x 16 cols; blockIdx%8 -> XCD so each XCD's gather set is 3.2 MB,
// L2-resident), radix-partition CSR build, bf16 MFMA matmuls.
// ---------------------------------------------------------------------------

typedef __attribute__((ext_vector_type(8))) short short8;
typedef __attribute__((ext_vector_type(4))) float float4v;

#define BKT 512       // nodes per bucket (dst >> 9)
#define NBMAX 256     // max buckets held in LDS (NB = 196 here)
#define NS 8          // column slices (== XCD count)
#define SC 16         // columns per slice (NS*SC == 128)

__device__ __forceinline__ float b2f_lo(unsigned int u) {
    return __uint_as_float(u << 16);
}
__device__ __forceinline__ float b2f_hi(unsigned int u) {
    return __uint_as_float(u & 0xffff0000u);
}
__device__ __forceinline__ unsigned short f2b(float f) {
    unsigned int u = __float_as_uint(f);
    return (unsigned short)((u + 0x7fffu + ((u >> 16) & 1u)) >> 16);  // RNE
}

// ---------------- edge-index dtype detection ----------------
__global__ void detect_i64_kernel(const unsigned int* ei, int* flag) {
    if (threadIdx.x == 0) {
        int is64 = 1;
        for (int e = 0; e < 64; ++e)
            if (ei[2 * e + 1] != 0u) { is64 = 0; break; }
        *flag = is64;
    }
}

__device__ __forceinline__ int edge_at(const int* ei32, int is64, long long pos) {
    if (is64) return (int)(((const long long*)ei32)[pos]);
    return ei32[pos];
}

// unpack edge_index into src/dst i32 arrays (coalesced)
__global__ void econv_kernel(const int* __restrict__ ei, const int* __restrict__ flag,
                             int* __restrict__ srcs, int* __restrict__ dsts, int E) {
    int e = blockIdx.x * blockDim.x + threadIdx.x;
    if (e >= E) return;
    int is64 = *flag;
    srcs[e] = edge_at(ei, is64, e);
    dsts[e] = edge_at(ei, is64, (long long)E + e);
}

// ---------------- radix partition pass 1: per-(block,bucket) histogram ----------------
__global__ __launch_bounds__(256) void part_hist_kernel(
        const int* __restrict__ dsts, int* __restrict__ bh, int E, int NB, int PB) {
    __shared__ int h[NBMAX];
    const int g = blockIdx.x, tid = threadIdx.x;
    for (int i = tid; i < NB; i += 256) h[i] = 0;
    __syncthreads();
    const int e0 = g * PB, e1 = min(e0 + PB, E);
    for (int e = e0 + tid; e < e1; e += 256)
        atomicAdd(&h[dsts[e] >> 9], 1);
    __syncthreads();
    for (int i = tid; i < NB; i += 256) bh[i * gridDim.x + g] = h[i];
}

// ---------------- generic multi-block exclusive scan ----------------
__global__ __launch_bounds__(1024) void scan1_kernel(
        const int* __restrict__ in, int* __restrict__ out,
        int* __restrict__ partial, int n) {
    __shared__ int sm[1024];
    const int t = threadIdx.x;
    const int i = blockIdx.x * 1024 + t;
    int v = (i < n) ? in[i] : 0;
    sm[t] = v;
    __syncthreads();
#pragma unroll
    for (int off = 1; off < 1024; off <<= 1) {
        int x = (t >= off) ? sm[t - off] : 0;
        __syncthreads();
        sm[t] += x;
        __syncthreads();
    }
    if (i < n) out[i] = sm[t] - v;
    if (t == 1023) partial[blockIdx.x] = sm[1023];
}

__global__ __launch_bounds__(128) void scan2_kernel(
        int* __restrict__ partial, int* __restrict__ blockoff, int g1) {
    __shared__ int sm[128];
    const int t = threadIdx.x;
    int v = (t < g1) ? partial[t] : 0;
    sm[t] = v;
    __syncthreads();
#pragma unroll
    for (int off = 1; off < 128; off <<= 1) {
        int x = (t >= off) ? sm[t - off] : 0;
        __syncthreads();
        sm[t] += x;
        __syncthreads();
    }
    blockoff[t] = sm[t] - v;
}

__global__ __launch_bounds__(1024) void scan3g_kernel(
        int* __restrict__ a, const int* __restrict__ blockoff, int n) {
    int i = blockIdx.x * 1024 + threadIdx.x;
    if (i < n) a[i] += blockoff[blockIdx.x];
}

// ---------------- pass 2: scatter edges into bucket-contiguous staging ----------------
// staged entry: (dlocal<<17) | src   (dlocal<512 -> 9 bits; src<2^17)
__global__ __launch_bounds__(256) void part_scatter_kernel(
        const int* __restrict__ dsts, const int* __restrict__ srcs,
        const int* __restrict__ bhs, unsigned int* __restrict__ staged,
        int E, int NB, int PB) {
    __shared__ int cur[NBMAX];
    const int g = blockIdx.x, tid = threadIdx.x;
    for (int i = tid; i < NB; i += 256) cur[i] = bhs[i * gridDim.x + g];
    __syncthreads();
    const int e0 = g * PB, e1 = min(e0 + PB, E);
    for (int e = e0 + tid; e < e1; e += 256) {
        int d = dsts[e];
        int s = srcs[e];
        int b = d >> 9;
        int p = atomicAdd(&cur[b], 1);
        staged[p] = ((unsigned int)(d & (BKT - 1)) << 17) | (unsigned int)s;
    }
}

// ---------------- pass 3: per-bucket counting sort -> offs + csr ----------------
__global__ __launch_bounds__(256) void csr_local_kernel(
        const unsigned int* __restrict__ staged, const int* __restrict__ bhs,
        int* __restrict__ offs, int* __restrict__ csr, int N, int E, int NB, int G2) {
    __shared__ int hist[BKT];
    __shared__ int cur[BKT];
    const int b = blockIdx.x;
    const int tid = threadIdx.x;
    const int start = bhs[b * G2];
    const int end = (b + 1 < NB) ? bhs[(b + 1) * G2] : E;
    const int node0 = b * BKT;
    for (int i = tid; i < BKT; i += 256) hist[i] = 0;
    __syncthreads();
    for (int i = start + tid; i < end; i += 256)
        atomicAdd(&hist[staged[i] >> 17], 1);
    __syncthreads();
    const int i0 = tid * 2, i1 = i0 + 1;
    for (int off = 1; off < BKT; off <<= 1) {
        int v0 = (i0 >= off) ? hist[i0 - off] : 0;
        int v1 = (i1 >= off) ? hist[i1 - off] : 0;
        __syncthreads();
        hist[i0] += v0;
        hist[i1] += v1;
        __syncthreads();
    }
    for (int i = tid; i < BKT; i += 256) {
        int node = node0 + i;
        if (node < N) {
            int e0 = start + ((i == 0) ? 0 : hist[i - 1]);
            offs[node] = e0;
            cur[i] = e0;
        }
    }
    if (b == NB - 1 && tid == 0) offs[N] = E;
    __syncthreads();
    for (int i = start + tid; i < end; i += 256) {
        unsigned int v = staged[i];
        int dl = v >> 17;
        int src = (int)(v & 0x1ffff);
        int p = atomicAdd(&cur[dl], 1);
        csr[p] = src;
    }
}

// ---------------- conversions ----------------
__global__ void xconv_kernel(const float* __restrict__ x, unsigned short* __restrict__ xb,
                             int total_real, int total_pad) {
    int i = blockIdx.x * blockDim.x + threadIdx.x;
    if (i >= total_pad) return;
    xb[i] = (i < total_real) ? f2b(x[i]) : (unsigned short)0;
}

// Pack W[K x KOUT] (f32 row-major) into MFMA-B fragment order.
__global__ void packw_kernel(const float* __restrict__ W, unsigned short* __restrict__ out,
                             int K, int KOUT) {
    const int KS = K / 32;
    const int total = (KOUT / 16) * KS * 64;
    int id = blockIdx.x * blockDim.x + threadIdx.x;
    if (id >= total) return;
    const int l = id & 63;
    const int s = (id >> 6) % KS;
    const int t = id / (KS * 64);
    const int kbase = s * 32 + ((l >> 4) << 3);
    const int n = t * 16 + (l & 15);
#pragma unroll
    for (int j = 0; j < 8; ++j)
        out[(long long)id * 8 + j] = f2b(W[(long long)(kbase + j) * KOUT + n]);
}

// ---------------- XCD-sliced aggregation ----------------
// H stored slice-major: Hs[s][node][SC] (s = col/SC). Block handles 32 nodes
// for one slice; slice = blockIdx%8 -> round-robin XCD assignment keeps each
// XCD's gather working set at Mpad*SC*2 = 3.2 MB (L2-resident).
// 8 lanes per node, 2 cols per lane (4B packed bf16 loads).
__global__ __launch_bounds__(256) void aggz_sliced_kernel(
        const unsigned short* __restrict__ Hs, const int* __restrict__ offs,
        const int* __restrict__ csr, const float* __restrict__ eps,
        unsigned short* __restrict__ Z, int n, int Mp) {
    const int s  = blockIdx.x & (NS - 1);
    const int nb = blockIdx.x >> 3;
    const int node = nb * 32 + (threadIdx.x >> 3);
    const int c2 = (threadIdx.x & 7) << 1;
    if (node >= n) return;
    const unsigned short* base = Hs + (long long)s * Mp * SC;
    const int beg = offs[node];
    const int end = offs[node + 1];
    float s0 = 0.f, s1 = 0.f;
    int i = beg;
    for (; i + 3 < end; i += 4) {
        int j0 = csr[i], j1 = csr[i + 1], j2 = csr[i + 2], j3 = csr[i + 3];
        unsigned int u0 = *(const unsigned int*)(base + (long long)j0 * SC + c2);
        unsigned int u1 = *(const unsigned int*)(base + (long long)j1 * SC + c2);
        unsigned int u2 = *(const unsigned int*)(base + (long long)j2 * SC + c2);
        unsigned int u3 = *(const unsigned int*)(base + (long long)j3 * SC + c2);
        s0 += (b2f_lo(u0) + b2f_lo(u1)) + (b2f_lo(u2) + b2f_lo(u3));
        s1 += (b2f_hi(u0) + b2f_hi(u1)) + (b2f_hi(u2) + b2f_hi(u3));
    }
    for (; i < end; ++i) {
        int j0 = csr[i];
        unsigned int u0 = *(const unsigned int*)(base + (long long)j0 * SC + c2);
        s0 += b2f_lo(u0);
        s1 += b2f_hi(u0);
    }
    unsigned int uh = *(const unsigned int*)(base + (long long)node * SC + c2);
    const float e = 1.0f + eps[0];
    float z0 = fmaf(e, b2f_lo(uh), s0);
    float z1 = fmaf(e, b2f_hi(uh), s1);
    *(unsigned int*)(Z + ((long long)node << 7) + s * SC + c2) =
        ((unsigned int)f2b(z1) << 16) | (unsigned int)f2b(z0);
}

// ---------------- MFMA matmul (LDS-free, packed-B fragments) ----------------
// OUTSLICED: write bf16 output in slice-major layout (for aggz gathers).
template<int KIN, int KOUT, bool RELU, bool HASBIAS, bool OUTF32, bool OUTSLICED>
__global__ __launch_bounds__(256) void mm_mfma(
        const unsigned short* __restrict__ Zin, const unsigned short* __restrict__ Wp,
        const float* __restrict__ bias, void* __restrict__ outv, int Mreal, int Mp) {
    constexpr int KS = KIN / 32;
    constexpr int NT = KOUT / 16;
    const int tid = threadIdx.x;
    const int w = tid >> 6;
    const int l = tid & 63;
    const int lm = l & 15;
    const int lk = l >> 4;
    const long long arow = (long long)blockIdx.x * 64 + w * 16 + lm;
    const unsigned short* zrow = Zin + arow * KIN + lk * 8;

    float4v acc[NT];
#pragma unroll
    for (int t = 0; t < NT; ++t) acc[t] = (float4v){0.f, 0.f, 0.f, 0.f};

#pragma unroll
    for (int s = 0; s < KS; ++s) {
        short8 a = *(const short8*)(zrow + s * 32);
#pragma unroll
        for (int t = 0; t < NT; ++t) {
            short8 b = *(const short8*)(Wp + (long long)((t * KS + s) * 64 + l) * 8);
            acc[t] = __builtin_amdgcn_mfma_f32_16x16x32_bf16(a, b, acc[t], 0, 0, 0);
        }
    }

    const long long orow0 = (long long)blockIdx.x * 64 + w * 16 + lk * 4;
#pragma unroll
    for (int t = 0; t < NT; ++t) {
        const int n = t * 16 + lm;
        const float bv = HASBIAS ? bias[n] : 0.f;
#pragma unroll
        for (int r = 0; r < 4; ++r) {
            float v = acc[t][r] + bv;
            if (RELU) v = fmaxf(v, 0.f);
            const long long orow = orow0 + r;
            if (OUTF32) {
                if (orow < Mreal) ((float*)outv)[orow * KOUT + n] = v;
            } else if (OUTSLICED) {
                ((unsigned short*)outv)[((long long)(n >> 4) * Mp + orow) * SC + (n & 15)] = f2b(v);
            } else {
                ((unsigned short*)outv)[orow * KOUT + n] = f2b(v);
            }
        }
    }
}

extern "C" void kernel_launch(void* const* d_in, const int* in_sizes, int n_in,
                              void* d_out, int out_size, void* d_ws, size_t ws_size,
                              hipStream_t stream) {
    const float* x    = (const float*)d_in[0];
    const int*   ei   = (const int*)d_in[1];
    const float* Wemb = (const float*)d_in[2];
    const float* eps1 = (const float*)d_in[3];
    const float* w1a  = (const float*)d_in[4];
    const float* b1a  = (const float*)d_in[5];
    const float* w1b  = (const float*)d_in[6];
    const float* b1b  = (const float*)d_in[7];
    const float* eps2 = (const float*)d_in[8];
    const float* w2a  = (const float*)d_in[9];
    const float* b2a  = (const float*)d_in[10];
    const float* w2b  = (const float*)d_in[11];
    const float* b2b  = (const float*)d_in[12];
    const float* eps3 = (const float*)d_in[13];
    const float* w3a  = (const float*)d_in[14];
    const float* b3a  = (const float*)d_in[15];
    const float* w3b  = (const float*)d_in[16];
    const float* b3b  = (const float*)d_in[17];

    const int N = in_sizes[0] / 64;   // 100000
    const int E = in_sizes[1] / 2;    // 1600000
    const int Mpad = ((N + 63) / 64) * 64;
    const int NB = (N + BKT - 1) / BKT;   // 196
    const int G2 = 256;
    const int PB = (E + G2 - 1) / G2;
    const int BH = NB * G2;

    char* ws = (char*)d_ws;
    size_t off = 0;
    auto alloc = [&](size_t bytes) -> void* {
        void* p = ws + off;
        off = (off + bytes + 255) & ~(size_t)255;
        return p;
    };
    unsigned short* xb  = (unsigned short*)alloc((size_t)Mpad * 64 * 2);
    unsigned short* Hb  = (unsigned short*)alloc((size_t)Mpad * 128 * 2);  // slice-major
    unsigned short* Zb  = (unsigned short*)alloc((size_t)Mpad * 128 * 2);  // row-major
    unsigned short* Tb  = (unsigned short*)alloc((size_t)Mpad * 256 * 2);  // row-major
    unsigned short* pWe = (unsigned short*)alloc((size_t)64 * 128 * 2);
    unsigned short* p1a = (unsigned short*)alloc((size_t)128 * 128 * 2);
    unsigned short* p1b = (unsigned short*)alloc((size_t)128 * 128 * 2);
    unsigned short* p2a = (unsigned short*)alloc((size_t)128 * 256 * 2);
    unsigned short* p2b = (unsigned short*)alloc((size_t)256 * 128 * 2);
    unsigned short* p3a = (unsigned short*)alloc((size_t)128 * 256 * 2);
    unsigned short* p3b = (unsigned short*)alloc((size_t)256 * 128 * 2);
    int* offs = (int*)alloc((size_t)(N + 1) * 4);
    int* csr  = (int*)alloc((size_t)E * 4);
    int* bh   = (int*)alloc((size_t)BH * 4);
    int* bhs  = (int*)alloc((size_t)BH * 4);
    int* part = (int*)alloc(1024);
    int* boff = (int*)alloc(1024);
    int* flag = (int*)alloc(256);

    // CSR staging aliased into Tb (first real use of Tb is the mm phase).
    unsigned int* staged = (unsigned int*)Tb;
    int* dsts = (int*)(Tb + (size_t)E * 2);
    int* srcs = (int*)(Tb + (size_t)E * 4);

    // ---- CSR build ----
    detect_i64_kernel<<<1, 64, 0, stream>>>((const unsigned int*)ei, flag);
    econv_kernel<<<(E + 255) / 256, 256, 0, stream>>>(ei, flag, srcs, dsts, E);
    part_hist_kernel<<<G2, 256, 0, stream>>>(dsts, bh, E, NB, PB);
    const int G1 = (BH + 1023) / 1024;
    scan1_kernel<<<G1, 1024, 0, stream>>>(bh, bhs, part, BH);
    scan2_kernel<<<1, 128, 0, stream>>>(part, boff, G1);
    scan3g_kernel<<<G1, 1024, 0, stream>>>(bhs, boff, BH);
    part_scatter_kernel<<<G2, 256, 0, stream>>>(dsts, srcs, bhs, staged, E, NB, PB);
    csr_local_kernel<<<NB, 256, 0, stream>>>(staged, bhs, offs, csr, N, E, NB, G2);

    // ---- conversions / weight packing ----
    xconv_kernel<<<(Mpad * 64 + 255) / 256, 256, 0, stream>>>(x, xb, N * 64, Mpad * 64);
    auto packw = [&](const float* W, unsigned short* o, int K, int KOUT) {
        int tot = (KOUT / 16) * (K / 32) * 64;
        packw_kernel<<<(tot + 255) / 256, 256, 0, stream>>>(W, o, K, KOUT);
    };
    packw(Wemb, pWe, 64, 128);
    packw(w1a, p1a, 128, 128);
    packw(w1b, p1b, 128, 128);
    packw(w2a, p2a, 128, 256);
    packw(w2b, p2b, 256, 128);
    packw(w3a, p3a, 128, 256);
    packw(w3b, p3b, 256, 128);

    const int MMB = Mpad / 64;
    const int AGB = ((N + 31) / 32) * NS;  // 3125 * 8

    // ---- embed: H = x @ W_embed (sliced output) ----
    mm_mfma<64, 128, false, false, false, true><<<MMB, 256, 0, stream>>>(xb, pWe, nullptr, Hb, N, Mpad);

    // ---- layer 1 ----
    aggz_sliced_kernel<<<AGB, 256, 0, stream>>>(Hb, offs, csr, eps1, Zb, N, Mpad);
    mm_mfma<128, 128, true,  true, false, false><<<MMB, 256, 0, stream>>>(Zb, p1a, b1a, Tb, N, Mpad);
    mm_mfma<128, 128, false, true, false, true ><<<MMB, 256, 0, stream>>>(Tb, p1b, b1b, Hb, N, Mpad);

    // ---- layer 2 ----
    aggz_sliced_kernel<<<AGB, 256, 0, stream>>>(Hb, offs, csr, eps2, Zb, N, Mpad);
    mm_mfma<128, 256, true, true, false, false><<<MMB, 256, 0, stream>>>(Zb, p2a, b2a, Tb, N, Mpad);
    mm_mfma<256, 128, true, true, false, true ><<<MMB, 256, 0, stream>>>(Tb, p2b, b2b, Hb, N, Mpad);

    // ---- layer 3 ----
    aggz_sliced_kernel<<<AGB, 256, 0, stream>>>(Hb, offs, csr, eps3, Zb, N, Mpad);
    mm_mfma<128, 256, true, true, false, false><<<MMB, 256, 0, stream>>>(Zb, p3a, b3a, Tb, N, Mpad);
    mm_mfma<256, 128, true, true, true, false><<<MMB, 256, 0, stream>>>(Tb, p3b, b3b, d_out, N, Mpad);
}